// Round 4
// baseline (120.105 us; speedup 1.0000x reference)
//
#include <hip/hip_runtime.h>
#include <hip/hip_bf16.h>
#include <math.h>

#define FRAME_LEN 882
#define FRAME_HOP 441
#define NFFT 2048
#define NFRAMES 999
#define NBATCH 16
#define NMEL 60
#define WAVE_LEN 441000
#define PRE_EMPH 0.97f
#define EPS 1e-10f
#define NROWS (NBATCH * NFRAMES)     // 15984 = 999 panels x 16 rows
#define NPANEL 999
#define KPAD 1056                    // 33*32
#define NKC 33
#define PANEL_ELEMS (NKC * 512)      // 16896 bf16 per panel (frag-linear)
#define PANEL_BYTES (PANEL_ELEMS * 2) // 33792
#define PI_F 3.14159265358979323846f

// LDS index padding: +1 per 16 (PADI). Affine in every unrolled loop index
// used in this kernel -> folds to ds_read/ds_write immediate offsets (zero
// per-access VALU). Measured R2: conflict count 512K = b64 access minimum.
#define PADI(i) ((i) + ((i) >> 4))

// Frag-linear offset of (row m in panel, bin k)
__device__ __forceinline__ int frag_off(int m, int k) {
  return ((k >> 5) * 512) | (((k >> 3) & 3) * 128) | (m * 8) | (k & 7);
}

// Packed complex type
typedef float vf2 __attribute__((ext_vector_type(2)));
__device__ __forceinline__ vf2 mkv(float x, float y){ vf2 r; r.x = x; r.y = y; return r; }
__device__ __forceinline__ vf2 cmul(vf2 a, vf2 b){ return a.xx * b + mkv(-a.y, a.y) * b.yx; }
__device__ __forceinline__ vf2 rotni(vf2 z){ return mkv(z.y, -z.x); }  // z * (-i)

// Four consecutive DIF radix-2 stages (halves 8S,4S,2S,S), 16 elems/thread.
// Thread owns e_k = Q*16S + k*S + r. All twiddles from t1 = e^{-i*pi*r/(8S)}.
__device__ __forceinline__ void dif_group16(vf2* x, vf2 t1, bool zerohi) {
  const vf2 C81 = mkv(0.9238795325f, -0.3826834324f);
  const vf2 C82 = mkv(0.7071067812f, -0.7071067812f);
  const vf2 C83 = mkv(0.3826834324f, -0.9238795325f);
  // stage half = 8S
  vf2 w0 = t1, w1 = cmul(t1, C81), w2 = cmul(t1, C82), w3 = cmul(t1, C83);
  vf2 ws1[8] = {w0, w1, w2, w3, rotni(w0), rotni(w1), rotni(w2), rotni(w3)};
  if (zerohi) {
    // x[8..15] known zero: x[k] stays, x[k+8] = x[k]*w
#pragma unroll
    for (int k = 0; k < 8; ++k) x[k + 8] = cmul(x[k], ws1[k]);
  } else {
#pragma unroll
    for (int k = 0; k < 8; ++k) {
      vf2 u = x[k], v = x[k + 8];
      x[k] = u + v;
      x[k + 8] = cmul(u - v, ws1[k]);
    }
  }
  // stage half = 4S
  vf2 t2 = cmul(t1, t1);
  vf2 v1 = cmul(t2, C82);
  vf2 ws2[4] = {t2, v1, rotni(t2), rotni(v1)};
#pragma unroll
  for (int h = 0; h < 2; ++h) {
#pragma unroll
    for (int k = 0; k < 4; ++k) {
      vf2 u = x[h*8 + k], v = x[h*8 + k + 4];
      x[h*8 + k] = u + v;
      x[h*8 + k + 4] = cmul(u - v, ws2[k]);
    }
  }
  // stage half = 2S
  vf2 t4 = cmul(t2, t2);
  vf2 t4r = rotni(t4);
#pragma unroll
  for (int h = 0; h < 4; ++h) {
    vf2 a = x[h*4 + 0], b = x[h*4 + 2];
    x[h*4 + 0] = a + b; x[h*4 + 2] = cmul(a - b, t4);
    a = x[h*4 + 1]; b = x[h*4 + 3];
    x[h*4 + 1] = a + b; x[h*4 + 3] = cmul(a - b, t4r);
  }
  // stage half = S
  vf2 t8 = cmul(t4, t4);
#pragma unroll
  for (int j = 0; j < 8; ++j) {
    vf2 a = x[2*j], b = x[2*j + 1];
    x[2*j] = a + b; x[2*j + 1] = cmul(a - b, t8);
  }
}

// Final 3 DIF stages (halves 4,2,1) on 8 consecutive elements.
__device__ __forceinline__ void dif8(vf2* y) {
  const vf2 c1 = mkv(0.7071067812f, -0.7071067812f);
  const vf2 c3 = mkv(-0.7071067812f, -0.7071067812f);
  vf2 u, v;
  u=y[0]; v=y[4]; y[0]=u+v; y[4]=u-v;
  u=y[1]; v=y[5]; y[1]=u+v; y[5]=cmul(u-v, c1);
  u=y[2]; v=y[6]; y[2]=u+v; y[6]=rotni(u-v);
  u=y[3]; v=y[7]; y[3]=u+v; y[7]=cmul(u-v, c3);
  u=y[0]; v=y[2]; y[0]=u+v; y[2]=u-v;
  u=y[1]; v=y[3]; y[1]=u+v; y[3]=rotni(u-v);
  u=y[4]; v=y[6]; y[4]=u+v; y[6]=u-v;
  u=y[5]; v=y[7]; y[5]=u+v; y[7]=rotni(u-v);
  u=y[0]; v=y[1]; y[0]=u+v; y[1]=u-v;
  u=y[2]; v=y[3]; y[2]=u+v; y[3]=u-v;
  u=y[4]; v=y[5]; y[4]=u+v; y[5]=u-v;
  u=y[6]; v=y[7]; y[6]=u+v; y[7]=u-v;
}

// Kernel 1: NOW one 2048-pt frame-pair FFT per 128-thread block (was 2 per
// 256-thread block). Barriers couple only 2 waves of ONE FFT; LDS/block
// halves to 17408 B (9 blocks/CU capacity, finer tail granularity).
// Power phase re-partitioned: 8 CONSECUTIVE bins per thread -> frag offsets
// contiguous -> one 16B store per frame (was 16 scalar 2B stores).
// Blocks [8000,8064) do the filter->bf16 fragment conversion.
__global__ __launch_bounds__(128) void fft_pow_kernel(
    const float* __restrict__ wav, const float* __restrict__ filt,
    __hip_bfloat16* __restrict__ powrF, __hip_bfloat16* __restrict__ filtbF)
{
  __shared__ vf2 lds[NFFT + (NFFT >> 4)];   // 2176 vf2 = 17408 B
  const int id = blockIdx.x;

  if (id >= 8000) {
    // ---- filter conversion branch (64 blocks) ----
    const int mm = id - 8000;  // 0..63
    __hip_bfloat16* qp = filtbF + (size_t)(mm >> 4) * PANEL_ELEMS;
    const int m = mm & 15;
    for (int k = threadIdx.x; k < KPAD; k += 128) {
      float v = (mm < NMEL && k < 1025) ? filt[mm * 1025 + k] : 0.f;
      qp[frag_off(m, k)] = __float2bfloat16(v);
    }
    return;
  }

  const int tt = threadIdx.x;        // thread id within the FFT (0..127)

  const int P  = id;                 // frame-pair index 0..7999
  const int b  = P & 15;
  const int t0 = 2 * (P >> 4), t1f = t0 + 1;
  const bool has1 = (t1f < NFRAMES);
  const float* w = wav + (size_t)b * WAVE_LEN;
  const int s0 = t0 * FRAME_HOP;
  int s1 = t1f * FRAME_HOP;
  if (s1 > WAVE_LEN - FRAME_LEN) s1 = WAVE_LEN - FRAME_LEN;

  vf2 x[16];
  // ---- load + pre-emphasis + Hamming: element i = k*128 + tt ----
  {
    float sB, cB, sD, cD;
    __sincosf(6.283185307179586f * (float)tt / 881.0f, &sB, &cB);
    __sincosf(6.283185307179586f * 128.0f / 881.0f, &sD, &cD);
    vf2 cur  = mkv(cB, sB);
    vf2 step = mkv(cD, sD);
#pragma unroll
    for (int k = 0; k < 7; ++k) {    // k>=7 -> i>=896 > 881 -> zero
      int i = k * 128 + tt;
      float v1 = 0.f, v2 = 0.f;
      if (i < FRAME_LEN) {
        float win = 0.54f - 0.46f * cur.x;
        int s = s0 + i;
        float e1 = (s > 0) ? (w[s] - PRE_EMPH * w[s - 1]) : w[s];
        v1 = e1 * win;
        int ss = s1 + i;             // ss >= 441 > 0 always
        v2 = (w[ss] - PRE_EMPH * w[ss - 1]) * win;
      }
      x[k] = mkv(v1, v2);
      cur = cmul(cur, step);
    }
#pragma unroll
    for (int k = 7; k < 16; ++k) x[k] = mkv(0.f, 0.f);
  }

  // ---- G0: halves 1024,512,256,128 (S=128, r=tt): t1 = e^{-i*pi*tt/1024}
  {
    float sA, cA;
    __sincosf(-PI_F * (float)tt / 1024.0f, &sA, &cA);
    dif_group16(x, mkv(cA, sA), true);   // x[8..15] zero on entry
  }
#pragma unroll
  for (int k = 0; k < 16; ++k) lds[PADI(k * 128 + tt)] = x[k];
  __syncthreads();

  // ---- G1: halves 64,32,16,8 (S=8): Q = tt>>3, r = tt&7; t1 = e^{-i*pi*r/64}
  // In-place per-thread (reader == writer per location): no inner barrier.
  {
    const int Q = tt >> 3, r = tt & 7;
    const int base = Q * 128 + r;
#pragma unroll
    for (int k = 0; k < 16; ++k) x[k] = lds[PADI(base + k * 8)];
    float sA, cA;
    __sincosf(-PI_F * (float)r / 64.0f, &sA, &cA);
    dif_group16(x, mkv(cA, sA), false);
#pragma unroll
    for (int k = 0; k < 16; ++k) lds[PADI(base + k * 8)] = x[k];
  }
  __syncthreads();

  // ---- G2: halves 4,2,1 — two 8-point const-twiddle FFTs on consecutive
  // runs. Results are SCATTERED to natural bin positions:
  //   value at post-G2 array index i = 16*tt + jj is X[brev11(i)],
  //   brev11(16*tt+jj) = 128*rev4(jj) + rev7(tt).
  {
    vf2 ya[8], yb[8];
#pragma unroll
    for (int j = 0; j < 8; ++j) {
      ya[j] = lds[PADI(16 * tt + j)];
      yb[j] = lds[PADI(16 * tt + 8 + j)];
    }
    dif8(ya);
    dif8(yb);
    __syncthreads();                 // reads done everywhere before scatter
    const int r7 = (int)(__brev((unsigned)tt) >> 25);   // rev7(tt)
    const int RA[8] = {0, 8, 4, 12, 2, 10, 6, 14};      // rev4(j),   j=0..7
    const int RB[8] = {1, 9, 5, 13, 3, 11, 7, 15};      // rev4(8+j), j=0..7
#pragma unroll
    for (int j = 0; j < 8; ++j) {
      lds[PADI(RA[j] * 128 + r7)] = ya[j];
      lds[PADI(RB[j] * 128 + r7)] = yb[j];
    }
  }
  __syncthreads();

  // ---- power separation + bf16 store, 8 CONSECUTIVE bins per thread ----
  // lds[i] holds X[i] (natural order). Thread tt owns bins f = 8tt..8tt+7;
  // frag_off(m, 8tt)+j is contiguous for j=0..7 -> one dwordx4 store/frame.
  const int r0g = b * NFRAMES + t0;
  const int r1g = r0g + 1;
  __hip_bfloat16* q0 = powrF + (size_t)(r0g >> 4) * PANEL_ELEMS;
  const int m0 = r0g & 15;
  __hip_bfloat16* q1 = powrF + (size_t)(r1g >> 4) * PANEL_ELEMS;
  const int m1 = r1g & 15;

  typedef __attribute__((ext_vector_type(8))) short short8v;
  {
    const int fb = 8 * tt;           // 0..1016
    vf2 z[8], y[8];
#pragma unroll
    for (int j = 0; j < 8; ++j) z[j] = lds[PADI(fb + j)];
    if (tt == 0) {
#pragma unroll
      for (int j = 0; j < 8; ++j) y[j] = lds[PADI((NFFT - j) & (NFFT - 1))];
    } else {
#pragma unroll
      for (int j = 0; j < 8; ++j) y[j] = lds[PADI(NFFT - fb - j)];
    }
    union { short8v v; __hip_bfloat16 h[8]; } u0, u1;
#pragma unroll
    for (int j = 0; j < 8; ++j) {
      float f1r = z[j].x + y[j].x, f1i = z[j].y - y[j].y;
      float f2r = z[j].y + y[j].y, f2i = y[j].x - z[j].x;
      float pw1 = 0.25f * (f1r * f1r + f1i * f1i);
      float pw2 = 0.25f * (f2r * f2r + f2i * f2i);
      u0.h[j] = __float2bfloat16(pw1);
      u1.h[j] = __float2bfloat16(pw2);
    }
    *(short8v*)(q0 + frag_off(m0, fb)) = u0.v;
    if (has1) *(short8v*)(q1 + frag_off(m1, fb)) = u1.v;
  }
  if (tt == 0) {
    vf2 z = lds[PADI(1024)];         // bin 1024 self-conjugate
    q0[frag_off(m0, 1024)] = __float2bfloat16(z.x * z.x);
    if (has1) q1[frag_off(m1, 1024)] = __float2bfloat16(z.y * z.y);
  }
  // zero the K pads (1025..KPAD-1)
  if (tt < KPAD - 1025) {
    int f = 1025 + tt;
    q0[frag_off(m0, f)] = __float2bfloat16(0.f);
    if (has1) q1[frag_off(m1, f)] = __float2bfloat16(0.f);
  }
}

// Kernel 2: mel GEMM with A panel staged to LDS via async global_load_lds
// (unchanged from R3).
typedef __attribute__((ext_vector_type(8))) short short8x;
typedef __attribute__((ext_vector_type(4))) float float4x;

__global__ __launch_bounds__(256) void melgemm_kernel(
    const __hip_bfloat16* __restrict__ powrF,
    const __hip_bfloat16* __restrict__ filtbF,
    float* __restrict__ logmelT)
{
  __shared__ __hip_bfloat16 As[PANEL_ELEMS];      // 33792 B, linear frag order
  const int tid  = threadIdx.x;
  const int wave = tid >> 6, lane = tid & 63;
  const int p = blockIdx.x;                       // panel = rows [16p, 16p+16)
  const __hip_bfloat16* pA = powrF + (size_t)p * PANEL_ELEMS;

#pragma unroll
  for (int r = 0; r < 9; ++r) {
    const int off = r * 4096 + tid * 16;
    if (off < PANEL_BYTES) {
      __builtin_amdgcn_global_load_lds(
          (const __attribute__((address_space(1))) unsigned int*)
              ((const unsigned char*)pA + off),
          (__attribute__((address_space(3))) unsigned int*)
              ((unsigned char*)As + off),
          16, 0, 0);
    }
  }
  __syncthreads();   // drains vmcnt for the global_load_lds queue

  const __hip_bfloat16* pB = filtbF + (size_t)wave * PANEL_ELEMS + lane * 8;

  float4x acc0 = {0.f, 0.f, 0.f, 0.f};
  float4x acc1 = {0.f, 0.f, 0.f, 0.f};
#pragma unroll 4
  for (int kc = 0; kc < 16; ++kc) {
    short8x b0 = *(const short8x*)(pB + kc * 512);
    short8x b1 = *(const short8x*)(pB + (kc + 16) * 512);
    short8x a0 = *(const short8x*)(&As[kc * 512 + lane * 8]);
    short8x a1 = *(const short8x*)(&As[(kc + 16) * 512 + lane * 8]);
    acc0 = __builtin_amdgcn_mfma_f32_16x16x32_bf16(a0, b0, acc0, 0, 0, 0);
    acc1 = __builtin_amdgcn_mfma_f32_16x16x32_bf16(a1, b1, acc1, 0, 0, 0);
  }
  {
    short8x bf = *(const short8x*)(pB + 32 * 512);
    short8x a  = *(const short8x*)(&As[32 * 512 + lane * 8]);
    acc0 = __builtin_amdgcn_mfma_f32_16x16x32_bf16(a, bf, acc0, 0, 0, 0);
  }

  // C/D layout: col = lane&15 (mel), row = (lane>>4)*4 + reg (panel row)
  const int mel = wave * 16 + (lane & 15);
  const int rsub = (lane >> 4) * 4;
  if (mel < NMEL) {
#pragma unroll
    for (int reg = 0; reg < 4; ++reg) {
      int row = p * 16 + rsub + reg;
      float vv = acc0[reg] + acc1[reg];
      logmelT[(size_t)mel * NROWS + row] = __logf(vv + EPS);
    }
  }
}

// Kernel 3: stats on transposed logmel (unchanged).
__global__ __launch_bounds__(256) void stats_kernel(
    const float* __restrict__ lmT, float* __restrict__ out)
{
  __shared__ float red[4];
  const int j   = blockIdx.x;   // 0..89
  const int b   = blockIdx.y;   // 0..15
  const int tid = threadIdx.x;
  const int base = b * NFRAMES;
  const float inv_sq2 = 0.7071067811865475f;
  const bool v3 = (tid < NFRAMES - 768);

  float f0, f1, f2, f3;
  if (j < 30) {
    const float* e = lmT + (size_t)(2 * j) * NROWS + base;
    const float* o = lmT + (size_t)(2 * j + 1) * NROWS + base;
    f0 = (e[tid]       + o[tid])       * inv_sq2;
    f1 = (e[tid + 256] + o[tid + 256]) * inv_sq2;
    f2 = (e[tid + 512] + o[tid + 512]) * inv_sq2;
    f3 = v3 ? (e[tid + 768] + o[tid + 768]) * inv_sq2 : 0.f;
  } else if (j < 60) {
    const int m = j - 30;
    const float* e = lmT + (size_t)(2 * m) * NROWS + base;
    const float* o = lmT + (size_t)(2 * m + 1) * NROWS + base;
    auto dl = [&](int t) -> float {
      int tp = (t + 1 > NFRAMES - 1) ? (NFRAMES - 1) : (t + 1);
      int tm = (t - 1 < 0) ? 0 : (t - 1);
      return ((e[tp] + o[tp]) - (e[tm] + o[tm])) * inv_sq2;
    };
    f0 = dl(tid);
    f1 = dl(tid + 256);
    f2 = dl(tid + 512);
    f3 = v3 ? dl(tid + 768) : 0.f;
  } else {
    const int m = j - 60;
    const float* e = lmT + (size_t)(2 * m) * NROWS + base;
    const float* o = lmT + (size_t)(2 * m + 1) * NROWS + base;
    f0 = (e[tid]       - o[tid])       * inv_sq2;
    f1 = (e[tid + 256] - o[tid + 256]) * inv_sq2;
    f2 = (e[tid + 512] - o[tid + 512]) * inv_sq2;
    f3 = v3 ? (e[tid + 768] - o[tid + 768]) * inv_sq2 : 0.f;
  }

  float s = f0 + f1 + f2 + f3;
  for (int o2 = 32; o2 > 0; o2 >>= 1) s += __shfl_xor(s, o2, 64);
  if ((tid & 63) == 0) red[tid >> 6] = s;
  __syncthreads();
  float mean = (red[0] + red[1] + red[2] + red[3]) / (float)NFRAMES;
  __syncthreads();

  float d0 = f0 - mean, d1 = f1 - mean, d2 = f2 - mean;
  float d3 = v3 ? (f3 - mean) : 0.f;
  float s2 = d0 * d0 + d1 * d1 + d2 * d2 + d3 * d3;
  for (int o2 = 32; o2 > 0; o2 >>= 1) s2 += __shfl_xor(s2, o2, 64);
  if ((tid & 63) == 0) red[tid >> 6] = s2;
  __syncthreads();
  float var = (red[0] + red[1] + red[2] + red[3]) / (float)(NFRAMES - 1);

  if (tid == 0) {
    out[b * 180 + j]      = mean;
    out[b * 180 + 90 + j] = sqrtf(var);
  }
}

extern "C" void kernel_launch(void* const* d_in, const int* in_sizes, int n_in,
                              void* d_out, int out_size, void* d_ws, size_t ws_size,
                              hipStream_t stream) {
  const float* wav  = (const float*)d_in[0];   // (16, 441000) f32
  const float* filt = (const float*)d_in[1];   // (60, 1025) f32
  float* out = (float*)d_out;                  // (16, 180) f32

  // ws: powrF bf16 [999 panels][16896], filtbF bf16 [4][16896], logmelT f32 [60][NROWS]
  unsigned char* ws = (unsigned char*)d_ws;
  __hip_bfloat16* powrF  = (__hip_bfloat16*)(ws);
  size_t off = (size_t)NPANEL * PANEL_ELEMS * 2;              // 33,758,208
  __hip_bfloat16* filtbF = (__hip_bfloat16*)(ws + off);
  off += (size_t)4 * PANEL_ELEMS * 2;                         // +135,168
  float* logmelT = (float*)(ws + off);                        // +3,836,160 => ~37.7 MB

  fft_pow_kernel<<<8064, 128, 0, stream>>>(wav, filt, powrF, filtbF);
  melgemm_kernel<<<NPANEL, 256, 0, stream>>>(powrF, filtbF, logmelT);
  stats_kernel<<<dim3(90, NBATCH), 256, 0, stream>>>(logmelT, out);
}

// Round 6
// 112.876 us; speedup vs baseline: 1.0640x; 1.0640x over previous
//
#include <hip/hip_runtime.h>
#include <hip/hip_bf16.h>
#include <math.h>

#define FRAME_LEN 882
#define FRAME_HOP 441
#define NFFT 2048
#define NFRAMES 999
#define NBATCH 16
#define NMEL 60
#define WAVE_LEN 441000
#define PRE_EMPH 0.97f
#define EPS 1e-10f
#define NROWS (NBATCH * NFRAMES)     // 15984 = 999 panels x 16 rows
#define NPANEL 999
#define KPAD 1056                    // 33*32
#define NKC 33
#define PANEL_ELEMS (NKC * 512)      // 16896 bf16 per panel (frag-linear)
#define PANEL_BYTES (PANEL_ELEMS * 2) // 33792
#define PI_F 3.14159265358979323846f

// LDS index padding: +1 per 16 (PADI). Affine in every unrolled loop index
// used in this kernel -> folds to ds_read/ds_write immediate offsets (zero
// per-access VALU). Measured R2: conflict count 512K = b64 access minimum.
#define PADI(i) ((i) + ((i) >> 4))

// Frag-linear offset of (row m in panel, bin k)
__device__ __forceinline__ int frag_off(int m, int k) {
  return ((k >> 5) * 512) | (((k >> 3) & 3) * 128) | (m * 8) | (k & 7);
}

// Packed complex type
typedef float vf2 __attribute__((ext_vector_type(2)));
__device__ __forceinline__ vf2 mkv(float x, float y){ vf2 r; r.x = x; r.y = y; return r; }
__device__ __forceinline__ vf2 cmul(vf2 a, vf2 b){ return a.xx * b + mkv(-a.y, a.y) * b.yx; }
__device__ __forceinline__ vf2 rotni(vf2 z){ return mkv(z.y, -z.x); }  // z * (-i)

// Four consecutive DIF radix-2 stages (halves 8S,4S,2S,S), 16 elems/thread.
// Thread owns e_k = Q*16S + k*S + r. All twiddles from t1 = e^{-i*pi*r/(8S)}.
__device__ __forceinline__ void dif_group16(vf2* x, vf2 t1, bool zerohi) {
  const vf2 C81 = mkv(0.9238795325f, -0.3826834324f);
  const vf2 C82 = mkv(0.7071067812f, -0.7071067812f);
  const vf2 C83 = mkv(0.3826834324f, -0.9238795325f);
  // stage half = 8S
  vf2 w0 = t1, w1 = cmul(t1, C81), w2 = cmul(t1, C82), w3 = cmul(t1, C83);
  vf2 ws1[8] = {w0, w1, w2, w3, rotni(w0), rotni(w1), rotni(w2), rotni(w3)};
  if (zerohi) {
    // x[8..15] known zero: x[k] stays, x[k+8] = x[k]*w
#pragma unroll
    for (int k = 0; k < 8; ++k) x[k + 8] = cmul(x[k], ws1[k]);
  } else {
#pragma unroll
    for (int k = 0; k < 8; ++k) {
      vf2 u = x[k], v = x[k + 8];
      x[k] = u + v;
      x[k + 8] = cmul(u - v, ws1[k]);
    }
  }
  // stage half = 4S
  vf2 t2 = cmul(t1, t1);
  vf2 v1 = cmul(t2, C82);
  vf2 ws2[4] = {t2, v1, rotni(t2), rotni(v1)};
#pragma unroll
  for (int h = 0; h < 2; ++h) {
#pragma unroll
    for (int k = 0; k < 4; ++k) {
      vf2 u = x[h*8 + k], v = x[h*8 + k + 4];
      x[h*8 + k] = u + v;
      x[h*8 + k + 4] = cmul(u - v, ws2[k]);
    }
  }
  // stage half = 2S
  vf2 t4 = cmul(t2, t2);
  vf2 t4r = rotni(t4);
#pragma unroll
  for (int h = 0; h < 4; ++h) {
    vf2 a = x[h*4 + 0], b = x[h*4 + 2];
    x[h*4 + 0] = a + b; x[h*4 + 2] = cmul(a - b, t4);
    a = x[h*4 + 1]; b = x[h*4 + 3];
    x[h*4 + 1] = a + b; x[h*4 + 3] = cmul(a - b, t4r);
  }
  // stage half = S
  vf2 t8 = cmul(t4, t4);
#pragma unroll
  for (int j = 0; j < 8; ++j) {
    vf2 a = x[2*j], b = x[2*j + 1];
    x[2*j] = a + b; x[2*j + 1] = cmul(a - b, t8);
  }
}

// Final 3 DIF stages (halves 4,2,1) on 8 consecutive elements.
__device__ __forceinline__ void dif8(vf2* y) {
  const vf2 c1 = mkv(0.7071067812f, -0.7071067812f);
  const vf2 c3 = mkv(-0.7071067812f, -0.7071067812f);
  vf2 u, v;
  u=y[0]; v=y[4]; y[0]=u+v; y[4]=u-v;
  u=y[1]; v=y[5]; y[1]=u+v; y[5]=cmul(u-v, c1);
  u=y[2]; v=y[6]; y[2]=u+v; y[6]=rotni(u-v);
  u=y[3]; v=y[7]; y[3]=u+v; y[7]=cmul(u-v, c3);
  u=y[0]; v=y[2]; y[0]=u+v; y[2]=u-v;
  u=y[1]; v=y[3]; y[1]=u+v; y[3]=rotni(u-v);
  u=y[4]; v=y[6]; y[4]=u+v; y[6]=u-v;
  u=y[5]; v=y[7]; y[5]=u+v; y[7]=rotni(u-v);
  u=y[0]; v=y[1]; y[0]=u+v; y[1]=u-v;
  u=y[2]; v=y[3]; y[2]=u+v; y[3]=u-v;
  u=y[4]; v=y[5]; y[4]=u+v; y[5]=u-v;
  u=y[6]; v=y[7]; y[6]=u+v; y[7]=u-v;
}

// Kernel 1 (EXACT R3 version): blocks [0,4000) each run TWO 2048-pt
// frame-pair FFTs side-by-side (threads 0-127 / 128-255, separate 17 KB
// LDS regions, shared barriers). G2 scatters results to NATURAL bin order
// (de-bit-reversal at write time, affine addresses) so the power phase
// reads linearly. Blocks [4000,4064) do filter->bf16 conversion.
__global__ __launch_bounds__(256) void fft_pow_kernel(
    const float* __restrict__ wav, const float* __restrict__ filt,
    __hip_bfloat16* __restrict__ powrF, __hip_bfloat16* __restrict__ filtbF)
{
  __shared__ vf2 lds2[2][NFFT + (NFFT >> 4)];   // 2 x 17408 B = 34816 B
  const int id = blockIdx.x;

  if (id >= 4000) {
    // ---- filter conversion branch (64 blocks) ----
    const int mm = id - 4000;  // 0..63
    __hip_bfloat16* qp = filtbF + (size_t)(mm >> 4) * PANEL_ELEMS;
    const int m = mm & 15;
    for (int k = threadIdx.x; k < KPAD; k += 256) {
      float v = (mm < NMEL && k < 1025) ? filt[mm * 1025 + k] : 0.f;
      qp[frag_off(m, k)] = __float2bfloat16(v);
    }
    return;
  }

  const int t   = threadIdx.x;
  const int fid = t >> 7;            // which of the 2 FFTs in this block
  const int tt  = t & 127;           // thread id within the FFT (0..127)
  vf2* lds = lds2[fid];

  const int P  = id * 2 + fid;       // frame-pair index 0..7999
  const int b  = P & 15;
  const int t0 = 2 * (P >> 4), t1f = t0 + 1;
  const bool has1 = (t1f < NFRAMES);
  const float* w = wav + (size_t)b * WAVE_LEN;
  const int s0 = t0 * FRAME_HOP;
  int s1 = t1f * FRAME_HOP;
  if (s1 > WAVE_LEN - FRAME_LEN) s1 = WAVE_LEN - FRAME_LEN;

  vf2 x[16];
  // ---- load + pre-emphasis + Hamming: element i = k*128 + tt ----
  {
    float sB, cB, sD, cD;
    __sincosf(6.283185307179586f * (float)tt / 881.0f, &sB, &cB);
    __sincosf(6.283185307179586f * 128.0f / 881.0f, &sD, &cD);
    vf2 cur  = mkv(cB, sB);
    vf2 step = mkv(cD, sD);
#pragma unroll
    for (int k = 0; k < 7; ++k) {    // k>=7 -> i>=896 > 881 -> zero
      int i = k * 128 + tt;
      float v1 = 0.f, v2 = 0.f;
      if (i < FRAME_LEN) {
        float win = 0.54f - 0.46f * cur.x;
        int s = s0 + i;
        float e1 = (s > 0) ? (w[s] - PRE_EMPH * w[s - 1]) : w[s];
        v1 = e1 * win;
        int ss = s1 + i;             // ss >= 441 > 0 always
        v2 = (w[ss] - PRE_EMPH * w[ss - 1]) * win;
      }
      x[k] = mkv(v1, v2);
      cur = cmul(cur, step);
    }
#pragma unroll
    for (int k = 7; k < 16; ++k) x[k] = mkv(0.f, 0.f);
  }

  // ---- G0: halves 1024,512,256,128 (S=128, r=tt): t1 = e^{-i*pi*tt/1024}
  {
    float sA, cA;
    __sincosf(-PI_F * (float)tt / 1024.0f, &sA, &cA);
    dif_group16(x, mkv(cA, sA), true);   // x[8..15] zero on entry
  }
#pragma unroll
  for (int k = 0; k < 16; ++k) lds[PADI(k * 128 + tt)] = x[k];
  __syncthreads();

  // ---- G1: halves 64,32,16,8 (S=8): Q = tt>>3, r = tt&7; t1 = e^{-i*pi*r/64}
  // In-place per-thread (reader == writer per location): no inner barrier.
  {
    const int Q = tt >> 3, r = tt & 7;
    const int base = Q * 128 + r;
#pragma unroll
    for (int k = 0; k < 16; ++k) x[k] = lds[PADI(base + k * 8)];
    float sA, cA;
    __sincosf(-PI_F * (float)r / 64.0f, &sA, &cA);
    dif_group16(x, mkv(cA, sA), false);
#pragma unroll
    for (int k = 0; k < 16; ++k) lds[PADI(base + k * 8)] = x[k];
  }
  __syncthreads();

  // ---- G2: halves 4,2,1 — two 8-point const-twiddle FFTs on consecutive
  // runs. Results are SCATTERED to natural bin positions:
  //   value at post-G2 array index i = 16*tt + jj is X[brev11(i)],
  //   brev11(16*tt+jj) = 128*rev4(jj) + rev7(tt).
  {
    vf2 ya[8], yb[8];
#pragma unroll
    for (int j = 0; j < 8; ++j) {
      ya[j] = lds[PADI(16 * tt + j)];
      yb[j] = lds[PADI(16 * tt + 8 + j)];
    }
    dif8(ya);
    dif8(yb);
    __syncthreads();                 // reads done everywhere before scatter
    const int r7 = (int)(__brev((unsigned)tt) >> 25);   // rev7(tt)
    const int RA[8] = {0, 8, 4, 12, 2, 10, 6, 14};      // rev4(j),   j=0..7
    const int RB[8] = {1, 9, 5, 13, 3, 11, 7, 15};      // rev4(8+j), j=0..7
#pragma unroll
    for (int j = 0; j < 8; ++j) {
      lds[PADI(RA[j] * 128 + r7)] = ya[j];
      lds[PADI(RB[j] * 128 + r7)] = yb[j];
    }
  }
  __syncthreads();

  // ---- power separation + bf16 store in FRAGMENT order ----
  // lds[b] now holds X[b] directly: linear reads, no brev gather.
  const int r0g = b * NFRAMES + t0;
  const int r1g = r0g + 1;
  __hip_bfloat16* q0 = powrF + (size_t)(r0g >> 4) * PANEL_ELEMS;
  const int m0 = r0g & 15;
  __hip_bfloat16* q1 = powrF + (size_t)(r1g >> 4) * PANEL_ELEMS;
  const int m1 = r1g & 15;
#pragma unroll
  for (int c = 0; c < 8; ++c) {
    int f = c * 128 + tt;
    int mir = (NFFT - f) & (NFFT - 1);
    vf2 z = lds[PADI(f)];
    vf2 y = lds[PADI(mir)];
    float f1r = z.x + y.x, f1i = z.y - y.y;
    float f2r = z.y + y.y, f2i = y.x - z.x;
    float pw1 = 0.25f * (f1r * f1r + f1i * f1i);
    float pw2 = 0.25f * (f2r * f2r + f2i * f2i);
    q0[frag_off(m0, f)] = __float2bfloat16(pw1);
    if (has1) q1[frag_off(m1, f)] = __float2bfloat16(pw2);
  }
  if (tt == 0) {
    vf2 z = lds[PADI(1024)];         // bin 1024 self-conjugate
    q0[frag_off(m0, 1024)] = __float2bfloat16(z.x * z.x);
    if (has1) q1[frag_off(m1, 1024)] = __float2bfloat16(z.y * z.y);
  }
  // zero the K pads (1025..KPAD-1)
  if (tt < KPAD - 1025) {
    int f = 1025 + tt;
    q0[frag_off(m0, f)] = __float2bfloat16(0.f);
    if (has1) q1[frag_off(m1, f)] = __float2bfloat16(0.f);
  }
}

// Kernel 2: mel GEMM, 500 blocks x 2 panels each.
//  - B (filter fragments) loaded ONCE per block into 132 VGPRs (fully
//    unrolled K loop -> compile-time Breg indices, no scratch) and reused
//    for both panels: inner loop is pure ds_read_b128 + MFMA.
//  - A double-buffered in LDS (2 x 33792 B); next panel's A staged via
//    async global_load_lds BEFORE computing the current panel, so HBM
//    latency hides under compute. The inter-panel __syncthreads' vmcnt
//    drain is the prefetch completion.
typedef __attribute__((ext_vector_type(8))) short short8x;
typedef __attribute__((ext_vector_type(4))) float float4x;

#define PPB 2   // panels per block; grid = 500 covers 999 panels

__global__ __launch_bounds__(256) void melgemm_kernel(
    const __hip_bfloat16* __restrict__ powrF,
    const __hip_bfloat16* __restrict__ filtbF,
    float* __restrict__ logmelT)
{
  __shared__ __hip_bfloat16 As[2][PANEL_ELEMS];   // 2 x 33792 B = 67584 B
  const int tid  = threadIdx.x;
  const int wave = tid >> 6, lane = tid & 63;
  const int p0 = blockIdx.x * PPB;

  // ---- B panel into registers (33 x 16B per lane), reused across panels
  short8x Breg[NKC];
  {
    const __hip_bfloat16* pB = filtbF + (size_t)wave * PANEL_ELEMS + lane * 8;
#pragma unroll
    for (int kc = 0; kc < NKC; ++kc)
      Breg[kc] = *(const short8x*)(pB + kc * 512);
  }

  // ---- async stage of panel p into LDS buffer buf
  auto stage = [&](int buf, int p) {
    const unsigned char* src =
        (const unsigned char*)(powrF + (size_t)p * PANEL_ELEMS);
    unsigned char* dst = (unsigned char*)As[buf];
#pragma unroll
    for (int r = 0; r < 9; ++r) {
      const int off = r * 4096 + tid * 16;
      if (off < PANEL_BYTES) {
        __builtin_amdgcn_global_load_lds(
            (const __attribute__((address_space(1))) unsigned int*)(src + off),
            (__attribute__((address_space(3))) unsigned int*)(dst + off),
            16, 0, 0);
      }
    }
  };

  stage(0, p0);        // p0 <= 998 always (500*2 = 1000, block 499 -> 998)
  __syncthreads();     // drain: As[0] ready

  const int mel  = wave * 16 + (lane & 15);
  const int rsub = (lane >> 4) * 4;

  for (int i = 0; i < PPB; ++i) {
    const int p = p0 + i;
    if (p >= NPANEL) break;                          // block-uniform
    const bool more = (i + 1 < PPB) && (p + 1 < NPANEL);
    if (more) stage((i + 1) & 1, p + 1);             // issue next-panel loads

    const __hip_bfloat16* A = As[i & 1];
    float4x acc0 = {0.f, 0.f, 0.f, 0.f};
    float4x acc1 = {0.f, 0.f, 0.f, 0.f};
#pragma unroll
    for (int kc = 0; kc < 16; ++kc) {                // full unroll: Breg
      short8x a0 = *(const short8x*)(&A[kc * 512 + lane * 8]);       // stays
      short8x a1 = *(const short8x*)(&A[(kc + 16) * 512 + lane * 8]); // in regs
      acc0 = __builtin_amdgcn_mfma_f32_16x16x32_bf16(a0, Breg[kc], acc0, 0, 0, 0);
      acc1 = __builtin_amdgcn_mfma_f32_16x16x32_bf16(a1, Breg[kc + 16], acc1, 0, 0, 0);
    }
    {
      short8x a = *(const short8x*)(&A[32 * 512 + lane * 8]);
      acc0 = __builtin_amdgcn_mfma_f32_16x16x32_bf16(a, Breg[32], acc0, 0, 0, 0);
    }

    // C/D layout: col = lane&15 (mel), row = (lane>>4)*4 + reg (panel row)
    if (mel < NMEL) {
#pragma unroll
      for (int reg = 0; reg < 4; ++reg) {
        int row = p * 16 + rsub + reg;
        float vv = acc0[reg] + acc1[reg];
        logmelT[(size_t)mel * NROWS + row] = __logf(vv + EPS);
      }
    }
    if (more) __syncthreads();   // vmcnt drain = next-panel stage complete;
                                 // also all reads of As[i&1] are done
  }
}

// Kernel 3: stats on transposed logmel (unchanged).
__global__ __launch_bounds__(256) void stats_kernel(
    const float* __restrict__ lmT, float* __restrict__ out)
{
  __shared__ float red[4];
  const int j   = blockIdx.x;   // 0..89
  const int b   = blockIdx.y;   // 0..15
  const int tid = threadIdx.x;
  const int base = b * NFRAMES;
  const float inv_sq2 = 0.7071067811865475f;
  const bool v3 = (tid < NFRAMES - 768);

  float f0, f1, f2, f3;
  if (j < 30) {
    const float* e = lmT + (size_t)(2 * j) * NROWS + base;
    const float* o = lmT + (size_t)(2 * j + 1) * NROWS + base;
    f0 = (e[tid]       + o[tid])       * inv_sq2;
    f1 = (e[tid + 256] + o[tid + 256]) * inv_sq2;
    f2 = (e[tid + 512] + o[tid + 512]) * inv_sq2;
    f3 = v3 ? (e[tid + 768] + o[tid + 768]) * inv_sq2 : 0.f;
  } else if (j < 60) {
    const int m = j - 30;
    const float* e = lmT + (size_t)(2 * m) * NROWS + base;
    const float* o = lmT + (size_t)(2 * m + 1) * NROWS + base;
    auto dl = [&](int t) -> float {
      int tp = (t + 1 > NFRAMES - 1) ? (NFRAMES - 1) : (t + 1);
      int tm = (t - 1 < 0) ? 0 : (t - 1);
      return ((e[tp] + o[tp]) - (e[tm] + o[tm])) * inv_sq2;
    };
    f0 = dl(tid);
    f1 = dl(tid + 256);
    f2 = dl(tid + 512);
    f3 = v3 ? dl(tid + 768) : 0.f;
  } else {
    const int m = j - 60;
    const float* e = lmT + (size_t)(2 * m) * NROWS + base;
    const float* o = lmT + (size_t)(2 * m + 1) * NROWS + base;
    f0 = (e[tid]       - o[tid])       * inv_sq2;
    f1 = (e[tid + 256] - o[tid + 256]) * inv_sq2;
    f2 = (e[tid + 512] - o[tid + 512]) * inv_sq2;
    f3 = v3 ? (e[tid + 768] - o[tid + 768]) * inv_sq2 : 0.f;
  }

  float s = f0 + f1 + f2 + f3;
  for (int o2 = 32; o2 > 0; o2 >>= 1) s += __shfl_xor(s, o2, 64);
  if ((tid & 63) == 0) red[tid >> 6] = s;
  __syncthreads();
  float mean = (red[0] + red[1] + red[2] + red[3]) / (float)NFRAMES;
  __syncthreads();

  float d0 = f0 - mean, d1 = f1 - mean, d2 = f2 - mean;
  float d3 = v3 ? (f3 - mean) : 0.f;
  float s2 = d0 * d0 + d1 * d1 + d2 * d2 + d3 * d3;
  for (int o2 = 32; o2 > 0; o2 >>= 1) s2 += __shfl_xor(s2, o2, 64);
  if ((tid & 63) == 0) red[tid >> 6] = s2;
  __syncthreads();
  float var = (red[0] + red[1] + red[2] + red[3]) / (float)(NFRAMES - 1);

  if (tid == 0) {
    out[b * 180 + j]      = mean;
    out[b * 180 + 90 + j] = sqrtf(var);
  }
}

extern "C" void kernel_launch(void* const* d_in, const int* in_sizes, int n_in,
                              void* d_out, int out_size, void* d_ws, size_t ws_size,
                              hipStream_t stream) {
  const float* wav  = (const float*)d_in[0];   // (16, 441000) f32
  const float* filt = (const float*)d_in[1];   // (60, 1025) f32
  float* out = (float*)d_out;                  // (16, 180) f32

  // ws: powrF bf16 [999 panels][16896], filtbF bf16 [4][16896], logmelT f32 [60][NROWS]
  unsigned char* ws = (unsigned char*)d_ws;
  __hip_bfloat16* powrF  = (__hip_bfloat16*)(ws);
  size_t off = (size_t)NPANEL * PANEL_ELEMS * 2;              // 33,758,208
  __hip_bfloat16* filtbF = (__hip_bfloat16*)(ws + off);
  off += (size_t)4 * PANEL_ELEMS * 2;                         // +135,168
  float* logmelT = (float*)(ws + off);                        // +3,836,160 => ~37.7 MB

  fft_pow_kernel<<<4064, 256, 0, stream>>>(wav, filt, powrF, filtbF);
  melgemm_kernel<<<500, 256, 0, stream>>>(powrF, filtbF, logmelT);
  stats_kernel<<<dim3(90, NBATCH), 256, 0, stream>>>(logmelT, out);
}